// Round 3
// baseline (1445.480 us; speedup 1.0000x reference)
//
#include <hip/hip_runtime.h>
#include <math.h>

// ---------- helpers ----------
typedef __bf16 bf16x8 __attribute__((ext_vector_type(8)));
typedef float f32x4 __attribute__((ext_vector_type(4)));

__device__ __forceinline__ unsigned short f2b(float f) {
    unsigned u = __float_as_uint(f);
    u += 0x7fffu + ((u >> 16) & 1u);
    return (unsigned short)(u >> 16);
}
__device__ __forceinline__ float b2f(unsigned short h) {
    return __uint_as_float(((unsigned)h) << 16);
}
__device__ __forceinline__ float gelu_exact(float x) {
    return 0.5f * x * (1.0f + erff(x * 0.70710678118654752f));
}

// ---------- transpose f32 [R][C] -> bf16 [C][R] ----------
__global__ void transpose_f2b(const float* __restrict__ in,
                              unsigned short* __restrict__ out, int R, int Cc) {
    __shared__ float tile[32][33];
    int c0 = blockIdx.x * 32, r0 = blockIdx.y * 32;
    int tx = threadIdx.x & 31, ty = threadIdx.x >> 5; // 32 x 8
    for (int i = ty; i < 32; i += 8)
        tile[i][tx] = in[(size_t)(r0 + i) * Cc + c0 + tx];
    __syncthreads();
    for (int i = ty; i < 32; i += 8)
        out[(size_t)(c0 + i) * R + r0 + tx] = f2b(tile[tx][i]);
}

// ---------- LayerNorm over C=512, out bf16 ----------
// INBF=1: input bf16 ; INBF=0: input f32.  gains/biases f32.
template<int INBF>
__global__ __launch_bounds__(256) void ln_bf16(const void* __restrict__ xin,
    const float* __restrict__ g, const float* __restrict__ bb,
    unsigned short* __restrict__ out)
{
    int tok = blockIdx.x, t = threadIdx.x;
    float v0, v1;
    if (INBF) {
        unsigned u = ((const unsigned*)xin)[(size_t)tok * 256 + t];
        v0 = b2f((unsigned short)(u & 0xffff));
        v1 = b2f((unsigned short)(u >> 16));
    } else {
        float2 f = ((const float2*)xin)[(size_t)tok * 256 + t];
        v0 = f.x; v1 = f.y;
    }
    float s = v0 + v1, sq = v0 * v0 + v1 * v1;
    for (int off = 32; off; off >>= 1) {
        s  += __shfl_down(s, off);
        sq += __shfl_down(sq, off);
    }
    __shared__ float red[8];
    if ((t & 63) == 0) { red[t >> 6] = s; red[4 + (t >> 6)] = sq; }
    __syncthreads();
    float S  = red[0] + red[1] + red[2] + red[3];
    float SQ = red[4] + red[5] + red[6] + red[7];
    float mean = S * (1.0f / 512.0f);
    float var  = SQ * (1.0f / 512.0f) - mean * mean;
    float rstd = rsqrtf(var + 1e-5f);
    int c = t * 2;
    float y0 = (v0 - mean) * rstd * g[c]     + bb[c];
    float y1 = (v1 - mean) * rstd * g[c + 1] + bb[c + 1];
    ((unsigned*)out)[(size_t)tok * 256 + t] = (unsigned)f2b(y0) | ((unsigned)f2b(y1) << 16);
}

// ---------- GEMM: A[M][K] bf16, Bt[N][K] bf16 -> C[M][N] ----------
// 128x128 tile, 4 waves, 16x16x32 MFMA.
// RESID: 0 none, 1 add f32 residual, 2 add bf16 residual.
template<int ACT, int BIAS, int RESID, int OUTBF>
__global__ __launch_bounds__(256) void gemm_bf16k(
    const unsigned short* __restrict__ A, const unsigned short* __restrict__ Bt,
    const float* __restrict__ bias, const void* Rres,
    void* Cout, int M, int N, int K)
{
    __shared__ __align__(16) unsigned short As[128][40];
    __shared__ __align__(16) unsigned short Bs[128][40];
    int t = threadIdx.x;
    int bm = blockIdx.y, bn = blockIdx.x;
    int wave = t >> 6, lane = t & 63;
    int wm = wave >> 1, wn = wave & 1;
    int l15 = lane & 15, kg = lane >> 4;
    f32x4 acc[4][4];
    #pragma unroll
    for (int i = 0; i < 4; i++)
        #pragma unroll
        for (int j = 0; j < 4; j++)
            acc[i][j] = (f32x4){0.f, 0.f, 0.f, 0.f};
    int r0 = t >> 2, quad = t & 3;
    const size_t aBase = (size_t)(bm * 128) * K;
    const size_t bBase = (size_t)(bn * 128) * K;
    for (int kt = 0; kt < K; kt += 32) {
        #pragma unroll
        for (int rr = 0; rr < 128; rr += 64) {
            int r = r0 + rr;
            uint4 av = *(const uint4*)(A  + aBase + (size_t)r * K + kt + quad * 8);
            *(uint4*)&As[r][quad * 8] = av;
            uint4 bv = *(const uint4*)(Bt + bBase + (size_t)r * K + kt + quad * 8);
            *(uint4*)&Bs[r][quad * 8] = bv;
        }
        __syncthreads();
        bf16x8 aF[4], bF[4];
        #pragma unroll
        for (int i = 0; i < 4; i++)
            aF[i] = *(const bf16x8*)&As[wm * 64 + i * 16 + l15][kg * 8];
        #pragma unroll
        for (int j = 0; j < 4; j++)
            bF[j] = *(const bf16x8*)&Bs[wn * 64 + j * 16 + l15][kg * 8];
        #pragma unroll
        for (int i = 0; i < 4; i++)
            #pragma unroll
            for (int j = 0; j < 4; j++)
                acc[i][j] = __builtin_amdgcn_mfma_f32_16x16x32_bf16(aF[i], bF[j], acc[i][j], 0, 0, 0);
        __syncthreads();
    }
    #pragma unroll
    for (int i = 0; i < 4; i++) {
        #pragma unroll
        for (int j = 0; j < 4; j++) {
            #pragma unroll
            for (int rg = 0; rg < 4; rg++) {
                int row = bm * 128 + wm * 64 + i * 16 + kg * 4 + rg;
                int col = bn * 128 + wn * 64 + j * 16 + l15;
                float v = acc[i][j][rg];
                if (BIAS) v += bias[col];
                if (ACT == 1) v = gelu_exact(v);
                if (RESID == 1) v += ((const float*)Rres)[(size_t)row * N + col];
                if (RESID == 2) v += b2f(((const unsigned short*)Rres)[(size_t)row * N + col]);
                if (OUTBF) ((unsigned short*)Cout)[(size_t)row * N + col] = f2b(v);
                else       ((float*)Cout)[(size_t)row * N + col] = v;
            }
        }
    }
}

// ---------- RoPE + normalize + fold scale, split qkv ----------
__global__ __launch_bounds__(256) void rope_qkv_ct(
    const float* __restrict__ qkv, const float* __restrict__ ls,
    float* __restrict__ qn, float* __restrict__ kn, float* __restrict__ vout)
{
    int tok = blockIdx.x;           // b*64+p
    int b = tok >> 6, p = tok & 63;
    int t = threadIdx.x;
    int h = t >> 5, r = t & 31;
    const float* base = qkv + (size_t)tok * 1536;
    float q0 = base[h * 64 + 2 * r], q1 = base[h * 64 + 2 * r + 1];
    float k0 = base[512 + h * 64 + 2 * r], k1 = base[512 + h * 64 + 2 * r + 1];
    int i = p >> 3, j = p & 7;
    int f = (r < 16) ? r : (r - 16);
    float mult = (r < 16) ? (float)i : (float)j;
    float freq = expf(-(float)f * (logf(10000.0f) / 16.0f));
    float ang = mult * freq;
    float sn, cs; sincosf(ang, &sn, &cs);
    float qr0 = q0 * cs - q1 * sn, qr1 = q0 * sn + q1 * cs;
    float kr0 = k0 * cs - k1 * sn, kr1 = k0 * sn + k1 * cs;
    float sq = qr0 * qr0 + qr1 * qr1;
    float sk = kr0 * kr0 + kr1 * kr1;
    for (int off = 16; off; off >>= 1) {
        sq += __shfl_xor(sq, off, 32);
        sk += __shfl_xor(sk, off, 32);
    }
    float scale = expf(fminf(ls[h], 4.6052f));
    float qf = scale / fmaxf(sqrtf(sq), 1e-12f);
    float kf = 1.0f  / fmaxf(sqrtf(sk), 1e-12f);
    size_t o = (((size_t)(b * 8 + h) * 64) + p) * 64 + 2 * r;
    qn[o] = qr0 * qf; qn[o + 1] = qr1 * qf;
    kn[o] = kr0 * kf; kn[o + 1] = kr1 * kf;
    int c0 = 2 * t;
    int vh = c0 >> 6, vd = c0 & 63;
    size_t vo = (((size_t)(b * 8 + vh) * 64) + p) * 64 + vd;
    vout[vo]     = base[1024 + c0];
    vout[vo + 1] = base[1024 + c0 + 1];
}

// ---------- CT attention (q,k pre-normalized&scaled) + residual ----------
__global__ __launch_bounds__(256) void attn_ct(
    const float* __restrict__ qn, const float* __restrict__ kn, const float* __restrict__ v,
    const float* __restrict__ ct_in, float* __restrict__ ct_out)
{
    int bh = blockIdx.x; int b = bh >> 3, h = bh & 7;
    int t = threadIdx.x;
    __shared__ __align__(16) float Sq[64 * 64];
    __shared__ __align__(16) float Sk[64 * 64];
    __shared__ __align__(16) float Ss[64 * 64];
    const float* qb = qn + (size_t)bh * 4096;
    const float* kb = kn + (size_t)bh * 4096;
    const float* vb = v  + (size_t)bh * 4096;
    for (int idx = t; idx < 1024; idx += 256) {
        ((float4*)Sq)[idx] = ((const float4*)qb)[idx];
        ((float4*)Sk)[idx] = ((const float4*)kb)[idx];
    }
    __syncthreads();
    int i = t >> 2, q4 = t & 3;
    {
        float acc[16];
        #pragma unroll
        for (int jj = 0; jj < 16; jj++) acc[jj] = 0.f;
        for (int k = 0; k < 64; k++) {
            float qv = Sq[i * 64 + k];
            #pragma unroll
            for (int jj = 0; jj < 16; jj++)
                acc[jj] += qv * Sk[(q4 * 16 + jj) * 64 + k];
        }
        float mx = -1e30f;
        #pragma unroll
        for (int jj = 0; jj < 16; jj++) mx = fmaxf(mx, acc[jj]);
        for (int off = 1; off < 4; off <<= 1) mx = fmaxf(mx, __shfl_xor(mx, off, 4));
        float sum = 0.f;
        #pragma unroll
        for (int jj = 0; jj < 16; jj++) { acc[jj] = expf(acc[jj] - mx); sum += acc[jj]; }
        for (int off = 1; off < 4; off <<= 1) sum += __shfl_xor(sum, off, 4);
        float inv = 1.f / sum;
        #pragma unroll
        for (int jj = 0; jj < 16; jj++) Ss[i * 64 + q4 * 16 + jj] = acc[jj] * inv;
    }
    __syncthreads();
    {
        int d0 = q4 * 16;
        float acc[16];
        #pragma unroll
        for (int dd = 0; dd < 16; dd++) acc[dd] = 0.f;
        for (int j = 0; j < 64; j++) {
            float pP = Ss[i * 64 + j];
            #pragma unroll
            for (int dd = 0; dd < 16; dd++) acc[dd] += pP * vb[j * 64 + d0 + dd];
        }
        size_t orow = ((size_t)(b * 64 + i)) * 512 + h * 64 + d0;
        #pragma unroll
        for (int dd = 0; dd < 16; dd++) ct_out[orow + dd] = ct_in[orow + dd] + acc[dd];
    }
}

// ---------- assemble z (bf16) = [ct_token ; 64 window pixels], f32 sources ----------
__global__ void assemble_z(const float* __restrict__ x, const float* __restrict__ ctf,
                           unsigned short* __restrict__ z) {
    int gid = blockIdx.x * 256 + threadIdx.x;   // 512*65*128 groups of 4
    if (gid >= 512 * 65 * 128) return;
    int c4 = gid & 127, tk = gid >> 7;
    int win = tk / 65, tok = tk - win * 65;
    float4 v;
    if (tok == 0) {
        v = ((const float4*)ctf)[(size_t)win * 128 + c4];
    } else {
        int p = tok - 1;
        int b = win >> 6, wh = (win >> 3) & 7, ww = win & 7;
        size_t pix = ((size_t)(b * 64 + wh * 8 + (p >> 3)) * 64) + ww * 8 + (p & 7);
        v = ((const float4*)x)[pix * 128 + c4];
    }
    ushort4 u;
    u.x = f2b(v.x); u.y = f2b(v.y); u.z = f2b(v.z); u.w = f2b(v.w);
    ((ushort4*)z)[gid] = u;
}

// ---------- CPB: tb[225][8], f32 weights ----------
__global__ void cpb_tb(const float* __restrict__ w1, const float* __restrict__ b1,
                       const float* __restrict__ w2, float* __restrict__ tb) {
    int pos = blockIdx.x;   // 0..224
    int t = threadIdx.x;
    int a = pos / 15, bq = pos % 15;
    float t0 = ((float)(a  - 7)) / 7.0f * 8.0f;
    float t1 = ((float)(bq - 7)) / 7.0f * 8.0f;
    float l8 = log2f(8.0f);
    float x0 = copysignf(log2f(fabsf(t0) + 1.0f) / l8, t0);
    float x1 = copysignf(log2f(fabsf(t1) + 1.0f) / l8, t1);
    __shared__ float acc8[8];
    if (t < 8) acc8[t] = 0.f;
    __syncthreads();
    float partial[8] = {0, 0, 0, 0, 0, 0, 0, 0};
    for (int u = t; u < 512; u += 256) {
        float hv = fmaxf(x0 * w1[u] + x1 * w1[512 + u] + b1[u], 0.0f);
        #pragma unroll
        for (int hh = 0; hh < 8; hh++) partial[hh] += hv * w2[u * 8 + hh];
    }
    for (int hh = 0; hh < 8; hh++) atomicAdd(&acc8[hh], partial[hh]);
    __syncthreads();
    if (t < 8) tb[pos * 8 + t] = acc8[t];
}

// ---------- bias[8][65][65] ----------
__global__ void bias_fill(const float* __restrict__ tb, float* __restrict__ bias) {
    int idx = blockIdx.x * 256 + threadIdx.x;
    if (idx >= 8 * 65 * 65) return;
    int h = idx / 4225, rem = idx % 4225;
    int i = rem / 65, j = rem % 65;
    float val = 0.f;
    if (i > 0 && j > 0) {
        int ii = i - 1, jj = j - 1;
        int d0 = (ii >> 3) - (jj >> 3) + 7;
        int d1 = (ii & 7) - (jj & 7) + 7;
        float xv = tb[(d0 * 15 + d1) * 8 + h];
        val = 16.0f / (1.0f + expf(-xv));
    }
    bias[idx] = val;
}

// ---------- window attention (chunk of 128 windows, local indexing) ----------
__global__ __launch_bounds__(256) void attn_win(
    const unsigned short* __restrict__ qkv, const float* __restrict__ ls,
    const float* __restrict__ bias, unsigned short* __restrict__ obuf)
{
    int win = blockIdx.x >> 3, h = blockIdx.x & 7;   // win is chunk-local
    int t = threadIdx.x;
    __shared__ __align__(16) float Sq[65 * 64];
    __shared__ __align__(16) float Sk[68 * 64];
    __shared__ __align__(16) float Ss[65 * 68];
    __shared__ __align__(16) unsigned short Sv[65 * 64];
    __shared__ float qfac[65], kfac[65];
    const unsigned short* base = qkv + (size_t)win * 65 * 1536 + h * 64;
    for (int idx = t; idx < 65 * 16; idx += 256) {
        int r = idx >> 4, d4 = (idx & 15) * 4;
        const unsigned short* rp = base + (size_t)r * 1536 + d4;
        ushort4 uq = *(const ushort4*)rp;
        ushort4 uk = *(const ushort4*)(rp + 512);
        ushort4 uv = *(const ushort4*)(rp + 1024);
        int o = r * 64 + d4;
        Sq[o] = b2f(uq.x); Sq[o + 1] = b2f(uq.y); Sq[o + 2] = b2f(uq.z); Sq[o + 3] = b2f(uq.w);
        Sk[o] = b2f(uk.x); Sk[o + 1] = b2f(uk.y); Sk[o + 2] = b2f(uk.z); Sk[o + 3] = b2f(uk.w);
        *(ushort4*)&Sv[o] = uv;
    }
    for (int idx = t; idx < 3 * 64; idx += 256) Sk[65 * 64 + idx] = 0.f;
    __syncthreads();
    if (t < 65) {
        float sq = 0.f, sk = 0.f;
        for (int d = 0; d < 64; d++) {
            float a = Sq[t * 64 + d]; sq += a * a;
            float b = Sk[t * 64 + d]; sk += b * b;
        }
        float scale = expf(fminf(ls[h], 4.6052f));
        qfac[t] = scale / fmaxf(sqrtf(sq), 1e-12f);
        kfac[t] = 1.0f  / fmaxf(sqrtf(sk), 1e-12f);
    }
    __syncthreads();
    {
        int jq = t & 3, j0 = jq * 17;
        int jcnt = (65 - j0 < 17) ? (65 - j0) : 17;
        for (int i = t >> 2; i < 65; i += 64) {
            float acc[17];
            #pragma unroll
            for (int jj = 0; jj < 17; jj++) acc[jj] = 0.f;
            for (int k = 0; k < 64; k++) {
                float qv = Sq[i * 64 + k];
                #pragma unroll
                for (int jj = 0; jj < 17; jj++)
                    acc[jj] += qv * Sk[(j0 + jj) * 64 + k];
            }
            for (int jj = 0; jj < jcnt; jj++) {
                int j = j0 + jj;
                Ss[i * 68 + j] = acc[jj] * qfac[i] * kfac[j] + bias[(size_t)h * 4225 + i * 65 + j];
            }
        }
    }
    __syncthreads();
    if (t < 65) {
        float mx = -1e30f;
        for (int j = 0; j < 65; j++) mx = fmaxf(mx, Ss[t * 68 + j]);
        float sum = 0.f;
        for (int j = 0; j < 65; j++) { float e = expf(Ss[t * 68 + j] - mx); Ss[t * 68 + j] = e; sum += e; }
        float inv = 1.f / sum;
        for (int j = 0; j < 65; j++) Ss[t * 68 + j] *= inv;
    }
    __syncthreads();
    {
        int dq = t & 3, d0 = dq * 16;
        for (int i = t >> 2; i < 65; i += 64) {
            float acc[16];
            #pragma unroll
            for (int dd = 0; dd < 16; dd++) acc[dd] = 0.f;
            for (int j = 0; j < 65; j++) {
                float pP = Ss[i * 68 + j];
                #pragma unroll
                for (int dd = 0; dd < 16; dd++) acc[dd] += pP * b2f(Sv[j * 64 + d0 + dd]);
            }
            unsigned short* op = obuf + ((size_t)(win * 65 + i)) * 512 + h * 64 + d0;
            #pragma unroll
            for (int dd = 0; dd < 16; dd++) op[dd] = f2b(acc[dd]);
        }
    }
}

// ---------- window reverse: z[:,1:,:] (bf16) -> x_out f32 ----------
__global__ void reverse_z(const unsigned short* __restrict__ z, float* __restrict__ out) {
    int gid = blockIdx.x * 256 + threadIdx.x;   // 8*64*64*128 groups of 4
    if (gid >= 8 * 64 * 64 * 128) return;
    int c4 = gid & 127, pix = gid >> 7;
    int b = pix >> 12, rem = pix & 4095;
    int hh = rem >> 6, w_ = rem & 63;
    int win = b * 64 + (hh >> 3) * 8 + (w_ >> 3);
    int tok = 1 + (hh & 7) * 8 + (w_ & 7);
    ushort4 u = ((const ushort4*)z)[((size_t)(win * 65 + tok)) * 128 + c4];
    float4 v;
    v.x = b2f(u.x); v.y = b2f(u.y); v.z = b2f(u.z); v.w = b2f(u.w);
    ((float4*)out)[gid] = v;
}

extern "C" void kernel_launch(void* const* d_in, const int* in_sizes, int n_in,
                              void* d_out, int out_size, void* d_ws, size_t ws_size,
                              hipStream_t stream)
{
    const float* x        = (const float*)d_in[0];
    const float* ct       = (const float*)d_in[1];
    const float* w_qkv_ct = (const float*)d_in[2];
    const float* ls_ct    = (const float*)d_in[3];
    const float* g_ct1    = (const float*)d_in[4];
    const float* b_ct1    = (const float*)d_in[5];
    const float* g_ct2    = (const float*)d_in[6];
    const float* b_ct2    = (const float*)d_in[7];
    const float* w1_ct    = (const float*)d_in[8];
    const float* b1_ct    = (const float*)d_in[9];
    const float* w2_ct    = (const float*)d_in[10];
    const float* b2_ct    = (const float*)d_in[11];
    const float* w_qkv_w  = (const float*)d_in[12];
    const float* w_proj   = (const float*)d_in[13];
    const float* b_proj   = (const float*)d_in[14];
    const float* ls_w     = (const float*)d_in[15];
    const float* g_w1     = (const float*)d_in[16];
    const float* b_w1     = (const float*)d_in[17];
    const float* g_w2     = (const float*)d_in[18];
    const float* b_w2     = (const float*)d_in[19];
    const float* cpb_w1   = (const float*)d_in[20];
    const float* cpb_b1   = (const float*)d_in[21];
    const float* cpb_w2   = (const float*)d_in[22];
    const float* w1_w     = (const float*)d_in[23];
    const float* b1_w     = (const float*)d_in[24];
    const float* w2_w     = (const float*)d_in[25];
    const float* b2_w     = (const float*)d_in[26];

    char* wsb = (char*)d_ws;
    size_t off = 0;
    auto alloc = [&](size_t bytes) -> void* {
        void* p = (void*)(wsb + off);
        off += (bytes + 255) & ~((size_t)255);
        return p;
    };
    // --- layout, total ~99 MB ---
    unsigned short* wqkvct_t = (unsigned short*)alloc((size_t)1536 * 512 * 2);
    unsigned short* w1ct_t   = (unsigned short*)alloc((size_t)2048 * 512 * 2);
    unsigned short* w2ct_t   = (unsigned short*)alloc((size_t)512 * 2048 * 2);
    unsigned short* wqkvw_t  = (unsigned short*)alloc((size_t)1536 * 512 * 2);
    unsigned short* wproj_t  = (unsigned short*)alloc((size_t)512 * 512 * 2);
    unsigned short* w1w_t    = (unsigned short*)alloc((size_t)2048 * 512 * 2);
    unsigned short* w2w_t    = (unsigned short*)alloc((size_t)512 * 2048 * 2);
    unsigned short* h_ct     = (unsigned short*)alloc((size_t)512 * 512 * 2);
    float* qkv_ct  = (float*)alloc((size_t)512 * 1536 * 4);
    float* qn_ct   = (float*)alloc((size_t)8 * 8 * 64 * 64 * 4);
    float* kn_ct   = (float*)alloc((size_t)8 * 8 * 64 * 64 * 4);
    float* v_ct    = (float*)alloc((size_t)8 * 8 * 64 * 64 * 4);
    float* ct_work = (float*)alloc((size_t)512 * 512 * 4);
    unsigned short* midc = (unsigned short*)alloc((size_t)512 * 2048 * 2);
    float* tb    = (float*)alloc((size_t)225 * 8 * 4);
    float* biasw = (float*)alloc((size_t)8 * 65 * 65 * 4);
    unsigned short* z    = (unsigned short*)alloc((size_t)33280 * 512 * 2);   // 34.1 MB bf16 residual stream
    unsigned short* h2c  = (unsigned short*)alloc((size_t)8320 * 512 * 2);    // 8.5 MB per-chunk LN out
    unsigned short* qkvc = (unsigned short*)alloc((size_t)8320 * 1536 * 2);   // 25.6 MB per-chunk qkv
    unsigned short* obufc = (unsigned short*)alloc((size_t)8320 * 512 * 2);   // 8.5 MB per-chunk attn out
    unsigned short* midw = qkvc;   // alias: qkvc+obufc (34,078,720 B exact) dead before MLP mid written

    // weight transposes (f32 [R][C] -> bf16 [C][R], K-major for GEMM B)
    transpose_f2b<<<dim3(48, 16), 256, 0, stream>>>(w_qkv_ct, wqkvct_t, 512, 1536);
    transpose_f2b<<<dim3(64, 16), 256, 0, stream>>>(w1_ct, w1ct_t, 512, 2048);
    transpose_f2b<<<dim3(16, 64), 256, 0, stream>>>(w2_ct, w2ct_t, 2048, 512);
    transpose_f2b<<<dim3(48, 16), 256, 0, stream>>>(w_qkv_w, wqkvw_t, 512, 1536);
    transpose_f2b<<<dim3(16, 16), 256, 0, stream>>>(w_proj, wproj_t, 512, 512);
    transpose_f2b<<<dim3(64, 16), 256, 0, stream>>>(w1_w, w1w_t, 512, 2048);
    transpose_f2b<<<dim3(16, 64), 256, 0, stream>>>(w2_w, w2w_t, 2048, 512);

    // --- CT branch ---
    ln_bf16<0><<<512, 256, 0, stream>>>(ct, g_ct1, b_ct1, h_ct);
    gemm_bf16k<0, 0, 0, 0><<<dim3(12, 4), 256, 0, stream>>>(h_ct, wqkvct_t, nullptr, nullptr, qkv_ct, 512, 1536, 512);
    rope_qkv_ct<<<512, 256, 0, stream>>>(qkv_ct, ls_ct, qn_ct, kn_ct, v_ct);
    attn_ct<<<64, 256, 0, stream>>>(qn_ct, kn_ct, v_ct, ct, ct_work);
    ln_bf16<0><<<512, 256, 0, stream>>>(ct_work, g_ct2, b_ct2, h_ct);
    gemm_bf16k<1, 1, 0, 1><<<dim3(16, 4), 256, 0, stream>>>(h_ct, w1ct_t, b1_ct, nullptr, midc, 512, 2048, 512);
    gemm_bf16k<0, 1, 1, 0><<<dim3(4, 4), 256, 0, stream>>>(midc, w2ct_t, b2_ct, ct_work, ct_work, 512, 512, 2048);

    // --- window branch ---
    assemble_z<<<16640, 256, 0, stream>>>(x, ct_work, z);
    cpb_tb<<<225, 256, 0, stream>>>(cpb_w1, cpb_b1, cpb_w2, tb);
    bias_fill<<<133, 256, 0, stream>>>(tb, biasw);

    // QKV + attention + proj, 4 chunks of 128 windows (8320 rows each)
    for (int c = 0; c < 4; c++) {
        size_t rowoff = (size_t)c * 8320;
        ln_bf16<1><<<8320, 256, 0, stream>>>(z + rowoff * 512, g_w1, b_w1, h2c);
        gemm_bf16k<0, 0, 0, 1><<<dim3(12, 65), 256, 0, stream>>>(h2c, wqkvw_t, nullptr, nullptr, qkvc, 8320, 1536, 512);
        attn_win<<<1024, 256, 0, stream>>>(qkvc, ls_w, biasw, obufc);
        gemm_bf16k<0, 1, 2, 1><<<dim3(4, 65), 256, 0, stream>>>(obufc, wproj_t, b_proj, z + rowoff * 512, z + rowoff * 512, 8320, 512, 512);
    }
    // MLP, 4 chunks of 8320 rows; mid (8320x2048) aliases qkvc+obufc (dead now)
    for (int c = 0; c < 4; c++) {
        size_t rowoff = (size_t)c * 8320;
        ln_bf16<1><<<8320, 256, 0, stream>>>(z + rowoff * 512, g_w2, b_w2, h2c);
        gemm_bf16k<1, 1, 0, 1><<<dim3(16, 65), 256, 0, stream>>>(h2c, w1w_t, b1_w, nullptr, midw, 8320, 2048, 512);
        gemm_bf16k<0, 1, 2, 1><<<dim3(4, 65), 256, 0, stream>>>(midw, w2w_t, b2_w, z + rowoff * 512, z + rowoff * 512, 8320, 512, 2048);
    }
    reverse_z<<<16384, 256, 0, stream>>>(z, (float*)d_out);
}

// Round 4
// 1200.553 us; speedup vs baseline: 1.2040x; 1.2040x over previous
//
#include <hip/hip_runtime.h>
#include <math.h>

// ---------- helpers ----------
typedef __bf16 bf16x8 __attribute__((ext_vector_type(8)));
typedef float f32x4 __attribute__((ext_vector_type(4)));

__device__ __forceinline__ unsigned short f2b(float f) {
    unsigned u = __float_as_uint(f);
    u += 0x7fffu + ((u >> 16) & 1u);
    return (unsigned short)(u >> 16);
}
__device__ __forceinline__ float b2f(unsigned short h) {
    return __uint_as_float(((unsigned)h) << 16);
}
__device__ __forceinline__ float gelu_exact(float x) {
    return 0.5f * x * (1.0f + erff(x * 0.70710678118654752f));
}
// async global->LDS, 16 B per lane; LDS dest = wave-uniform base + lane*16
__device__ __forceinline__ void gl_lds16(const unsigned short* g, unsigned short* l) {
    __builtin_amdgcn_global_load_lds(
        (__attribute__((address_space(1))) const void*)g,
        (__attribute__((address_space(3))) void*)l, 16, 0, 0);
}

// ---------- transpose f32 [R][C] -> bf16 [C][R] ----------
__global__ void transpose_f2b(const float* __restrict__ in,
                              unsigned short* __restrict__ out, int R, int Cc) {
    __shared__ float tile[32][33];
    int c0 = blockIdx.x * 32, r0 = blockIdx.y * 32;
    int tx = threadIdx.x & 31, ty = threadIdx.x >> 5; // 32 x 8
    for (int i = ty; i < 32; i += 8)
        tile[i][tx] = in[(size_t)(r0 + i) * Cc + c0 + tx];
    __syncthreads();
    for (int i = ty; i < 32; i += 8)
        out[(size_t)(c0 + i) * R + r0 + tx] = f2b(tile[tx][i]);
}

// ---------- LayerNorm over C=512, out bf16 ----------
template<int INBF>
__global__ __launch_bounds__(256) void ln_bf16(const void* __restrict__ xin,
    const float* __restrict__ g, const float* __restrict__ bb,
    unsigned short* __restrict__ out)
{
    int tok = blockIdx.x, t = threadIdx.x;
    float v0, v1;
    if (INBF) {
        unsigned u = ((const unsigned*)xin)[(size_t)tok * 256 + t];
        v0 = b2f((unsigned short)(u & 0xffff));
        v1 = b2f((unsigned short)(u >> 16));
    } else {
        float2 f = ((const float2*)xin)[(size_t)tok * 256 + t];
        v0 = f.x; v1 = f.y;
    }
    float s = v0 + v1, sq = v0 * v0 + v1 * v1;
    for (int off = 32; off; off >>= 1) {
        s  += __shfl_down(s, off);
        sq += __shfl_down(sq, off);
    }
    __shared__ float red[8];
    if ((t & 63) == 0) { red[t >> 6] = s; red[4 + (t >> 6)] = sq; }
    __syncthreads();
    float S  = red[0] + red[1] + red[2] + red[3];
    float SQ = red[4] + red[5] + red[6] + red[7];
    float mean = S * (1.0f / 512.0f);
    float var  = SQ * (1.0f / 512.0f) - mean * mean;
    float rstd = rsqrtf(var + 1e-5f);
    int c = t * 2;
    float y0 = (v0 - mean) * rstd * g[c]     + bb[c];
    float y1 = (v1 - mean) * rstd * g[c + 1] + bb[c + 1];
    ((unsigned*)out)[(size_t)tok * 256 + t] = (unsigned)f2b(y0) | ((unsigned)f2b(y1) << 16);
}

// ---------- GEMM: A[M][K] bf16, Bt[N][K] bf16 -> C[M][N] ----------
// 128x128 tile, 4 waves, 16x16x32 MFMA, global_load_lds(16B) staging.
// RESID: 0 none, 1 add f32 residual, 2 add bf16 residual.
template<int ACT, int BIAS, int RESID, int OUTBF>
__global__ __launch_bounds__(256) void gemm_bf16k(
    const unsigned short* __restrict__ A, const unsigned short* __restrict__ Bt,
    const float* __restrict__ bias, const void* Rres,
    void* Cout, int M, int N, int K)
{
    __shared__ __align__(16) unsigned short As[128 * 32];   // unpadded: row*32 shorts (64 B/row)
    __shared__ __align__(16) unsigned short Bs[128 * 32];
    int t = threadIdx.x;
    int bm = blockIdx.y, bn = blockIdx.x;
    int wave = t >> 6, lane = t & 63;
    int wm = wave >> 1, wn = wave & 1;
    int l15 = lane & 15, kg = lane >> 4;
    f32x4 acc[4][4];
    #pragma unroll
    for (int i = 0; i < 4; i++)
        #pragma unroll
        for (int j = 0; j < 4; j++)
            acc[i][j] = (f32x4){0.f, 0.f, 0.f, 0.f};
    int r0 = t >> 2, c0 = (t & 3) * 8;
    const unsigned short* ga = A  + (size_t)(bm * 128) * K + (size_t)r0 * K + c0;
    const unsigned short* gb = Bt + (size_t)(bn * 128) * K + (size_t)r0 * K + c0;
    unsigned short* la = As + t * 8;   // thread writes LDS bytes [t*16, t*16+16)
    unsigned short* lb = Bs + t * 8;
    for (int kt = 0; kt < K; kt += 32) {
        gl_lds16(ga + kt, la);
        gl_lds16(ga + kt + (size_t)64 * K, la + 2048);
        gl_lds16(gb + kt, lb);
        gl_lds16(gb + kt + (size_t)64 * K, lb + 2048);
        __syncthreads();   // drains vmcnt -> staged data visible
        bf16x8 aF[4], bF[4];
        #pragma unroll
        for (int i = 0; i < 4; i++)
            aF[i] = *(const bf16x8*)&As[(wm * 64 + i * 16 + l15) * 32 + kg * 8];
        #pragma unroll
        for (int j = 0; j < 4; j++)
            bF[j] = *(const bf16x8*)&Bs[(wn * 64 + j * 16 + l15) * 32 + kg * 8];
        #pragma unroll
        for (int i = 0; i < 4; i++)
            #pragma unroll
            for (int j = 0; j < 4; j++)
                acc[i][j] = __builtin_amdgcn_mfma_f32_16x16x32_bf16(aF[i], bF[j], acc[i][j], 0, 0, 0);
        __syncthreads();   // all reads done before next iteration's async writes
    }
    #pragma unroll
    for (int i = 0; i < 4; i++) {
        #pragma unroll
        for (int j = 0; j < 4; j++) {
            #pragma unroll
            for (int rg = 0; rg < 4; rg++) {
                int row = bm * 128 + wm * 64 + i * 16 + kg * 4 + rg;
                int col = bn * 128 + wn * 64 + j * 16 + l15;
                float v = acc[i][j][rg];
                if (BIAS) v += bias[col];
                if (ACT == 1) v = gelu_exact(v);
                if (RESID == 1) v += ((const float*)Rres)[(size_t)row * N + col];
                if (RESID == 2) v += b2f(((const unsigned short*)Rres)[(size_t)row * N + col]);
                if (OUTBF) ((unsigned short*)Cout)[(size_t)row * N + col] = f2b(v);
                else       ((float*)Cout)[(size_t)row * N + col] = v;
            }
        }
    }
}

// ---------- RoPE + normalize + fold scale, split qkv ----------
__global__ __launch_bounds__(256) void rope_qkv_ct(
    const float* __restrict__ qkv, const float* __restrict__ ls,
    float* __restrict__ qn, float* __restrict__ kn, float* __restrict__ vout)
{
    int tok = blockIdx.x;           // b*64+p
    int b = tok >> 6, p = tok & 63;
    int t = threadIdx.x;
    int h = t >> 5, r = t & 31;
    const float* base = qkv + (size_t)tok * 1536;
    float q0 = base[h * 64 + 2 * r], q1 = base[h * 64 + 2 * r + 1];
    float k0 = base[512 + h * 64 + 2 * r], k1 = base[512 + h * 64 + 2 * r + 1];
    int i = p >> 3, j = p & 7;
    int f = (r < 16) ? r : (r - 16);
    float mult = (r < 16) ? (float)i : (float)j;
    float freq = expf(-(float)f * (logf(10000.0f) / 16.0f));
    float ang = mult * freq;
    float sn, cs; sincosf(ang, &sn, &cs);
    float qr0 = q0 * cs - q1 * sn, qr1 = q0 * sn + q1 * cs;
    float kr0 = k0 * cs - k1 * sn, kr1 = k0 * sn + k1 * cs;
    float sq = qr0 * qr0 + qr1 * qr1;
    float sk = kr0 * kr0 + kr1 * kr1;
    for (int off = 16; off; off >>= 1) {
        sq += __shfl_xor(sq, off, 32);
        sk += __shfl_xor(sk, off, 32);
    }
    float scale = expf(fminf(ls[h], 4.6052f));
    float qf = scale / fmaxf(sqrtf(sq), 1e-12f);
    float kf = 1.0f  / fmaxf(sqrtf(sk), 1e-12f);
    size_t o = (((size_t)(b * 8 + h) * 64) + p) * 64 + 2 * r;
    qn[o] = qr0 * qf; qn[o + 1] = qr1 * qf;
    kn[o] = kr0 * kf; kn[o + 1] = kr1 * kf;
    int c0 = 2 * t;
    int vh = c0 >> 6, vd = c0 & 63;
    size_t vo = (((size_t)(b * 8 + vh) * 64) + p) * 64 + vd;
    vout[vo]     = base[1024 + c0];
    vout[vo + 1] = base[1024 + c0 + 1];
}

// ---------- CT attention (q,k pre-normalized&scaled) + residual ----------
__global__ __launch_bounds__(256) void attn_ct(
    const float* __restrict__ qn, const float* __restrict__ kn, const float* __restrict__ v,
    const float* __restrict__ ct_in, float* __restrict__ ct_out)
{
    int bh = blockIdx.x; int b = bh >> 3, h = bh & 7;
    int t = threadIdx.x;
    __shared__ __align__(16) float Sq[64 * 64];
    __shared__ __align__(16) float Sk[64 * 64];
    __shared__ __align__(16) float Ss[64 * 64];
    const float* qb = qn + (size_t)bh * 4096;
    const float* kb = kn + (size_t)bh * 4096;
    const float* vb = v  + (size_t)bh * 4096;
    for (int idx = t; idx < 1024; idx += 256) {
        ((float4*)Sq)[idx] = ((const float4*)qb)[idx];
        ((float4*)Sk)[idx] = ((const float4*)kb)[idx];
    }
    __syncthreads();
    int i = t >> 2, q4 = t & 3;
    {
        float acc[16];
        #pragma unroll
        for (int jj = 0; jj < 16; jj++) acc[jj] = 0.f;
        for (int k = 0; k < 64; k++) {
            float qv = Sq[i * 64 + k];
            #pragma unroll
            for (int jj = 0; jj < 16; jj++)
                acc[jj] += qv * Sk[(q4 * 16 + jj) * 64 + k];
        }
        float mx = -1e30f;
        #pragma unroll
        for (int jj = 0; jj < 16; jj++) mx = fmaxf(mx, acc[jj]);
        for (int off = 1; off < 4; off <<= 1) mx = fmaxf(mx, __shfl_xor(mx, off, 4));
        float sum = 0.f;
        #pragma unroll
        for (int jj = 0; jj < 16; jj++) { acc[jj] = expf(acc[jj] - mx); sum += acc[jj]; }
        for (int off = 1; off < 4; off <<= 1) sum += __shfl_xor(sum, off, 4);
        float inv = 1.f / sum;
        #pragma unroll
        for (int jj = 0; jj < 16; jj++) Ss[i * 64 + q4 * 16 + jj] = acc[jj] * inv;
    }
    __syncthreads();
    {
        int d0 = q4 * 16;
        float acc[16];
        #pragma unroll
        for (int dd = 0; dd < 16; dd++) acc[dd] = 0.f;
        for (int j = 0; j < 64; j++) {
            float pP = Ss[i * 64 + j];
            #pragma unroll
            for (int dd = 0; dd < 16; dd++) acc[dd] += pP * vb[j * 64 + d0 + dd];
        }
        size_t orow = ((size_t)(b * 64 + i)) * 512 + h * 64 + d0;
        #pragma unroll
        for (int dd = 0; dd < 16; dd++) ct_out[orow + dd] = ct_in[orow + dd] + acc[dd];
    }
}

// ---------- assemble z (bf16) = [ct_token ; 64 window pixels], f32 sources ----------
__global__ void assemble_z(const float* __restrict__ x, const float* __restrict__ ctf,
                           unsigned short* __restrict__ z) {
    int gid = blockIdx.x * 256 + threadIdx.x;   // 512*65*128 groups of 4
    if (gid >= 512 * 65 * 128) return;
    int c4 = gid & 127, tk = gid >> 7;
    int win = tk / 65, tok = tk - win * 65;
    float4 v;
    if (tok == 0) {
        v = ((const float4*)ctf)[(size_t)win * 128 + c4];
    } else {
        int p = tok - 1;
        int b = win >> 6, wh = (win >> 3) & 7, ww = win & 7;
        size_t pix = ((size_t)(b * 64 + wh * 8 + (p >> 3)) * 64) + ww * 8 + (p & 7);
        v = ((const float4*)x)[pix * 128 + c4];
    }
    ushort4 u;
    u.x = f2b(v.x); u.y = f2b(v.y); u.z = f2b(v.z); u.w = f2b(v.w);
    ((ushort4*)z)[gid] = u;
}

// ---------- CPB: tb[225][8], f32 weights ----------
__global__ void cpb_tb(const float* __restrict__ w1, const float* __restrict__ b1,
                       const float* __restrict__ w2, float* __restrict__ tb) {
    int pos = blockIdx.x;   // 0..224
    int t = threadIdx.x;
    int a = pos / 15, bq = pos % 15;
    float t0 = ((float)(a  - 7)) / 7.0f * 8.0f;
    float t1 = ((float)(bq - 7)) / 7.0f * 8.0f;
    float l8 = log2f(8.0f);
    float x0 = copysignf(log2f(fabsf(t0) + 1.0f) / l8, t0);
    float x1 = copysignf(log2f(fabsf(t1) + 1.0f) / l8, t1);
    __shared__ float acc8[8];
    if (t < 8) acc8[t] = 0.f;
    __syncthreads();
    float partial[8] = {0, 0, 0, 0, 0, 0, 0, 0};
    for (int u = t; u < 512; u += 256) {
        float hv = fmaxf(x0 * w1[u] + x1 * w1[512 + u] + b1[u], 0.0f);
        #pragma unroll
        for (int hh = 0; hh < 8; hh++) partial[hh] += hv * w2[u * 8 + hh];
    }
    for (int hh = 0; hh < 8; hh++) atomicAdd(&acc8[hh], partial[hh]);
    __syncthreads();
    if (t < 8) tb[pos * 8 + t] = acc8[t];
}

// ---------- bias[8][65][65] ----------
__global__ void bias_fill(const float* __restrict__ tb, float* __restrict__ bias) {
    int idx = blockIdx.x * 256 + threadIdx.x;
    if (idx >= 8 * 65 * 65) return;
    int h = idx / 4225, rem = idx % 4225;
    int i = rem / 65, j = rem % 65;
    float val = 0.f;
    if (i > 0 && j > 0) {
        int ii = i - 1, jj = j - 1;
        int d0 = (ii >> 3) - (jj >> 3) + 7;
        int d1 = (ii & 7) - (jj & 7) + 7;
        float xv = tb[(d0 * 15 + d1) * 8 + h];
        val = 16.0f / (1.0f + expf(-xv));
    }
    bias[idx] = val;
}

// ---------- window attention via MFMA (chunk of 128 windows) ----------
// S = Q K^T (25 16x16 tiles, K=64), softmax rows, O = P V (20 tiles, K=96 padded).
// Sq/Sk: bf16 [80][72] (pad rows zero). SvT: V^T bf16 [64][104] (pad cols zero).
// Ss: f32 scores [65][68]. Sp: P bf16 [80][104], aliases Sq/Sk region (zeroed after QK).
__global__ __launch_bounds__(256) void attn_win(
    const unsigned short* __restrict__ qkv, const float* __restrict__ ls,
    const float* __restrict__ bias, unsigned short* __restrict__ obuf)
{
    int win = blockIdx.x >> 3, h = blockIdx.x & 7;   // chunk-local window
    int t = threadIdx.x;
    int wave = t >> 6, lane = t & 63, l15 = lane & 15, kg = lane >> 4;
    __shared__ __align__(16) unsigned short U[11520];     // 23040 B: Sq[5760] + Sk[5760]; reused as Sp[8320]
    __shared__ __align__(16) unsigned short SvT[64 * 104];
    __shared__ __align__(16) float Ss[65 * 68];
    __shared__ float qfac[65], kfac[65];
    unsigned short* Sq = U;
    unsigned short* Sk = U + 5760;
    unsigned short* Sp = U;

    // zero pad rows 65..79 of Sq,Sk (cols 0..71) and all of SvT
    for (int idx = t; idx < 15 * 18; idx += 256) {
        int r = 65 + idx / 18, c4 = (idx % 18) * 4;
        *(ushort4*)&Sq[r * 72 + c4] = (ushort4){0, 0, 0, 0};
        *(ushort4*)&Sk[r * 72 + c4] = (ushort4){0, 0, 0, 0};
    }
    for (int idx = t; idx < 64 * 26; idx += 256)
        *(ushort4*)&SvT[idx * 4] = (ushort4){0, 0, 0, 0};
    __syncthreads();
    // fill q,k (row-major) and v (transposed)
    const unsigned short* base = qkv + (size_t)win * 65 * 1536 + h * 64;
    for (int idx = t; idx < 65 * 16; idx += 256) {
        int r = idx >> 4, d4 = (idx & 15) * 4;
        const unsigned short* rp = base + (size_t)r * 1536 + d4;
        ushort4 uq = *(const ushort4*)rp;
        ushort4 uk = *(const ushort4*)(rp + 512);
        ushort4 uv = *(const ushort4*)(rp + 1024);
        *(ushort4*)&Sq[r * 72 + d4] = uq;
        *(ushort4*)&Sk[r * 72 + d4] = uk;
        SvT[(d4 + 0) * 104 + r] = uv.x;
        SvT[(d4 + 1) * 104 + r] = uv.y;
        SvT[(d4 + 2) * 104 + r] = uv.z;
        SvT[(d4 + 3) * 104 + r] = uv.w;
    }
    __syncthreads();
    // cosine norm factors
    if (t < 130) {
        int r = (t < 65) ? t : (t - 65);
        const unsigned short* row = ((t < 65) ? Sq : Sk) + r * 72;
        float s = 0.f;
        for (int d = 0; d < 64; d++) { float v = b2f(row[d]); s += v * v; }
        float f = 1.0f / fmaxf(sqrtf(s), 1e-12f);
        if (t < 65) qfac[r] = f * expf(fminf(ls[h], 4.6052f));
        else        kfac[r] = f;
    }
    __syncthreads();
    // S = Q K^T : 25 tiles
    for (int s = wave; s < 25; s += 4) {
        int tm = s / 5, tn = s % 5;
        f32x4 acc = (f32x4){0.f, 0.f, 0.f, 0.f};
        #pragma unroll
        for (int kk = 0; kk < 2; kk++) {
            bf16x8 aF = *(const bf16x8*)&Sq[(tm * 16 + l15) * 72 + kk * 32 + kg * 8];
            bf16x8 bF = *(const bf16x8*)&Sk[(tn * 16 + l15) * 72 + kk * 32 + kg * 8];
            acc = __builtin_amdgcn_mfma_f32_16x16x32_bf16(aF, bF, acc, 0, 0, 0);
        }
        #pragma unroll
        for (int rg = 0; rg < 4; rg++) {
            int i = tm * 16 + kg * 4 + rg, j = tn * 16 + l15;
            if (i < 65 && j < 65)
                Ss[i * 68 + j] = acc[rg] * qfac[i] * kfac[j] + bias[(size_t)h * 4225 + i * 65 + j];
        }
    }
    __syncthreads();
    // Sq/Sk dead; zero Sp (80x104) before softmax writes P
    for (int idx = t; idx < 80 * 26; idx += 256)
        *(ushort4*)&Sp[idx * 4] = (ushort4){0, 0, 0, 0};
    __syncthreads();
    // softmax per row, write P (bf16) into Sp
    if (t < 65) {
        float mx = -1e30f;
        for (int j = 0; j < 65; j++) mx = fmaxf(mx, Ss[t * 68 + j]);
        float sum = 0.f;
        for (int j = 0; j < 65; j++) { float e = expf(Ss[t * 68 + j] - mx); Ss[t * 68 + j] = e; sum += e; }
        float inv = 1.f / sum;
        for (int j = 0; j < 65; j++) Sp[t * 104 + j] = f2b(Ss[t * 68 + j] * inv);
    }
    __syncthreads();
    // O = P V : 20 tiles (5m x 4n), K=96
    for (int s = wave; s < 20; s += 4) {
        int tm = s >> 2, tn = s & 3;
        f32x4 acc = (f32x4){0.f, 0.f, 0.f, 0.f};
        #pragma unroll
        for (int kk = 0; kk < 3; kk++) {
            bf16x8 aF = *(const bf16x8*)&Sp[(tm * 16 + l15) * 104 + kk * 32 + kg * 8];
            bf16x8 bF = *(const bf16x8*)&SvT[(tn * 16 + l15) * 104 + kk * 32 + kg * 8];
            acc = __builtin_amdgcn_mfma_f32_16x16x32_bf16(aF, bF, acc, 0, 0, 0);
        }
        #pragma unroll
        for (int rg = 0; rg < 4; rg++) {
            int i = tm * 16 + kg * 4 + rg, d = tn * 16 + l15;
            if (i < 65)
                obuf[((size_t)(win * 65 + i)) * 512 + h * 64 + d] = f2b(acc[rg]);
        }
    }
}

// ---------- window reverse: z[:,1:,:] (bf16) -> x_out f32 ----------
__global__ void reverse_z(const unsigned short* __restrict__ z, float* __restrict__ out) {
    int gid = blockIdx.x * 256 + threadIdx.x;   // 8*64*64*128 groups of 4
    if (gid >= 8 * 64 * 64 * 128) return;
    int c4 = gid & 127, pix = gid >> 7;
    int b = pix >> 12, rem = pix & 4095;
    int hh = rem >> 6, w_ = rem & 63;
    int win = b * 64 + (hh >> 3) * 8 + (w_ >> 3);
    int tok = 1 + (hh & 7) * 8 + (w_ & 7);
    ushort4 u = ((const ushort4*)z)[((size_t)(win * 65 + tok)) * 128 + c4];
    float4 v;
    v.x = b2f(u.x); v.y = b2f(u.y); v.z = b2f(u.z); v.w = b2f(u.w);
    ((float4*)out)[gid] = v;
}

extern "C" void kernel_launch(void* const* d_in, const int* in_sizes, int n_in,
                              void* d_out, int out_size, void* d_ws, size_t ws_size,
                              hipStream_t stream)
{
    const float* x        = (const float*)d_in[0];
    const float* ct       = (const float*)d_in[1];
    const float* w_qkv_ct = (const float*)d_in[2];
    const float* ls_ct    = (const float*)d_in[3];
    const float* g_ct1    = (const float*)d_in[4];
    const float* b_ct1    = (const float*)d_in[5];
    const float* g_ct2    = (const float*)d_in[6];
    const float* b_ct2    = (const float*)d_in[7];
    const float* w1_ct    = (const float*)d_in[8];
    const float* b1_ct    = (const float*)d_in[9];
    const float* w2_ct    = (const float*)d_in[10];
    const float* b2_ct    = (const float*)d_in[11];
    const float* w_qkv_w  = (const float*)d_in[12];
    const float* w_proj   = (const float*)d_in[13];
    const float* b_proj   = (const float*)d_in[14];
    const float* ls_w     = (const float*)d_in[15];
    const float* g_w1     = (const float*)d_in[16];
    const float* b_w1     = (const float*)d_in[17];
    const float* g_w2     = (const float*)d_in[18];
    const float* b_w2     = (const float*)d_in[19];
    const float* cpb_w1   = (const float*)d_in[20];
    const float* cpb_b1   = (const float*)d_in[21];
    const float* cpb_w2   = (const float*)d_in[22];
    const float* w1_w     = (const float*)d_in[23];
    const float* b1_w     = (const float*)d_in[24];
    const float* w2_w     = (const float*)d_in[25];
    const float* b2_w     = (const float*)d_in[26];

    char* wsb = (char*)d_ws;
    size_t off = 0;
    auto alloc = [&](size_t bytes) -> void* {
        void* p = (void*)(wsb + off);
        off += (bytes + 255) & ~((size_t)255);
        return p;
    };
    // --- layout, total ~99 MB ---
    unsigned short* wqkvct_t = (unsigned short*)alloc((size_t)1536 * 512 * 2);
    unsigned short* w1ct_t   = (unsigned short*)alloc((size_t)2048 * 512 * 2);
    unsigned short* w2ct_t   = (unsigned short*)alloc((size_t)512 * 2048 * 2);
    unsigned short* wqkvw_t  = (unsigned short*)alloc((size_t)1536 * 512 * 2);
    unsigned short* wproj_t  = (unsigned short*)alloc((size_t)512 * 512 * 2);
    unsigned short* w1w_t    = (unsigned short*)alloc((size_t)2048 * 512 * 2);
    unsigned short* w2w_t    = (unsigned short*)alloc((size_t)512 * 2048 * 2);
    unsigned short* h_ct     = (unsigned short*)alloc((size_t)512 * 512 * 2);
    float* qkv_ct  = (float*)alloc((size_t)512 * 1536 * 4);
    float* qn_ct   = (float*)alloc((size_t)8 * 8 * 64 * 64 * 4);
    float* kn_ct   = (float*)alloc((size_t)8 * 8 * 64 * 64 * 4);
    float* v_ct    = (float*)alloc((size_t)8 * 8 * 64 * 64 * 4);
    float* ct_work = (float*)alloc((size_t)512 * 512 * 4);
    unsigned short* midc = (unsigned short*)alloc((size_t)512 * 2048 * 2);
    float* tb    = (float*)alloc((size_t)225 * 8 * 4);
    float* biasw = (float*)alloc((size_t)8 * 65 * 65 * 4);
    unsigned short* z    = (unsigned short*)alloc((size_t)33280 * 512 * 2);   // bf16 residual stream
    unsigned short* h2c  = (unsigned short*)alloc((size_t)8320 * 512 * 2);    // per-chunk LN out
    unsigned short* qkvc = (unsigned short*)alloc((size_t)8320 * 1536 * 2);   // per-chunk qkv
    unsigned short* obufc = (unsigned short*)alloc((size_t)8320 * 512 * 2);   // per-chunk attn out
    unsigned short* midw = qkvc;   // alias: qkvc+obufc (34,078,720 B) dead before MLP mid written

    // weight transposes (f32 [R][C] -> bf16 [C][R], K-major for GEMM B)
    transpose_f2b<<<dim3(48, 16), 256, 0, stream>>>(w_qkv_ct, wqkvct_t, 512, 1536);
    transpose_f2b<<<dim3(64, 16), 256, 0, stream>>>(w1_ct, w1ct_t, 512, 2048);
    transpose_f2b<<<dim3(16, 64), 256, 0, stream>>>(w2_ct, w2ct_t, 2048, 512);
    transpose_f2b<<<dim3(48, 16), 256, 0, stream>>>(w_qkv_w, wqkvw_t, 512, 1536);
    transpose_f2b<<<dim3(16, 16), 256, 0, stream>>>(w_proj, wproj_t, 512, 512);
    transpose_f2b<<<dim3(64, 16), 256, 0, stream>>>(w1_w, w1w_t, 512, 2048);
    transpose_f2b<<<dim3(16, 64), 256, 0, stream>>>(w2_w, w2w_t, 2048, 512);

    // --- CT branch ---
    ln_bf16<0><<<512, 256, 0, stream>>>(ct, g_ct1, b_ct1, h_ct);
    gemm_bf16k<0, 0, 0, 0><<<dim3(12, 4), 256, 0, stream>>>(h_ct, wqkvct_t, nullptr, nullptr, qkv_ct, 512, 1536, 512);
    rope_qkv_ct<<<512, 256, 0, stream>>>(qkv_ct, ls_ct, qn_ct, kn_ct, v_ct);
    attn_ct<<<64, 256, 0, stream>>>(qn_ct, kn_ct, v_ct, ct, ct_work);
    ln_bf16<0><<<512, 256, 0, stream>>>(ct_work, g_ct2, b_ct2, h_ct);
    gemm_bf16k<1, 1, 0, 1><<<dim3(16, 4), 256, 0, stream>>>(h_ct, w1ct_t, b1_ct, nullptr, midc, 512, 2048, 512);
    gemm_bf16k<0, 1, 1, 0><<<dim3(4, 4), 256, 0, stream>>>(midc, w2ct_t, b2_ct, ct_work, ct_work, 512, 512, 2048);

    // --- window branch ---
    assemble_z<<<16640, 256, 0, stream>>>(x, ct_work, z);
    cpb_tb<<<225, 256, 0, stream>>>(cpb_w1, cpb_b1, cpb_w2, tb);
    bias_fill<<<133, 256, 0, stream>>>(tb, biasw);

    // QKV + attention + proj, 4 chunks of 128 windows (8320 rows each)
    for (int c = 0; c < 4; c++) {
        size_t rowoff = (size_t)c * 8320;
        ln_bf16<1><<<8320, 256, 0, stream>>>(z + rowoff * 512, g_w1, b_w1, h2c);
        gemm_bf16k<0, 0, 0, 1><<<dim3(12, 65), 256, 0, stream>>>(h2c, wqkvw_t, nullptr, nullptr, qkvc, 8320, 1536, 512);
        attn_win<<<1024, 256, 0, stream>>>(qkvc, ls_w, biasw, obufc);
        gemm_bf16k<0, 1, 2, 1><<<dim3(4, 65), 256, 0, stream>>>(obufc, wproj_t, b_proj, z + rowoff * 512, z + rowoff * 512, 8320, 512, 512);
    }
    // MLP, 4 chunks of 8320 rows; mid (8320x2048) aliases qkvc+obufc (dead now)
    for (int c = 0; c < 4; c++) {
        size_t rowoff = (size_t)c * 8320;
        ln_bf16<1><<<8320, 256, 0, stream>>>(z + rowoff * 512, g_w2, b_w2, h2c);
        gemm_bf16k<1, 1, 0, 1><<<dim3(16, 65), 256, 0, stream>>>(h2c, w1w_t, b1_w, nullptr, midw, 8320, 2048, 512);
        gemm_bf16k<0, 1, 2, 1><<<dim3(4, 65), 256, 0, stream>>>(midw, w2w_t, b2_w, z + rowoff * 512, z + rowoff * 512, 8320, 512, 2048);
    }
    reverse_z<<<16384, 256, 0, stream>>>(z, (float*)d_out);
}

// Round 5
// 1046.689 us; speedup vs baseline: 1.3810x; 1.1470x over previous
//
#include <hip/hip_runtime.h>
#include <math.h>

// ---------- helpers ----------
typedef __bf16 bf16x8 __attribute__((ext_vector_type(8)));
typedef float f32x4 __attribute__((ext_vector_type(4)));

__device__ __forceinline__ unsigned short f2b(float f) {
    unsigned u = __float_as_uint(f);
    u += 0x7fffu + ((u >> 16) & 1u);
    return (unsigned short)(u >> 16);
}
__device__ __forceinline__ float b2f(unsigned short h) {
    return __uint_as_float(((unsigned)h) << 16);
}
__device__ __forceinline__ float gelu_exact(float x) {
    return 0.5f * x * (1.0f + erff(x * 0.70710678118654752f));
}
// async global->LDS, 16 B per lane; LDS dest = wave-uniform base + lane*16
__device__ __forceinline__ void gl_lds16(const unsigned short* g, unsigned short* l) {
    __builtin_amdgcn_global_load_lds(
        (__attribute__((address_space(1))) const void*)g,
        (__attribute__((address_space(3))) void*)l, 16, 0, 0);
}

// ---------- transpose f32 [R][C] -> bf16 [C][R] ----------
__global__ void transpose_f2b(const float* __restrict__ in,
                              unsigned short* __restrict__ out, int R, int Cc) {
    __shared__ float tile[32][33];
    int c0 = blockIdx.x * 32, r0 = blockIdx.y * 32;
    int tx = threadIdx.x & 31, ty = threadIdx.x >> 5; // 32 x 8
    for (int i = ty; i < 32; i += 8)
        tile[i][tx] = in[(size_t)(r0 + i) * Cc + c0 + tx];
    __syncthreads();
    for (int i = ty; i < 32; i += 8)
        out[(size_t)(c0 + i) * R + r0 + tx] = f2b(tile[tx][i]);
}

// ---------- LayerNorm over C=512, out bf16 ----------
template<int INBF>
__global__ __launch_bounds__(256) void ln_bf16(const void* __restrict__ xin,
    const float* __restrict__ g, const float* __restrict__ bb,
    unsigned short* __restrict__ out)
{
    int tok = blockIdx.x, t = threadIdx.x;
    float v0, v1;
    if (INBF) {
        unsigned u = ((const unsigned*)xin)[(size_t)tok * 256 + t];
        v0 = b2f((unsigned short)(u & 0xffff));
        v1 = b2f((unsigned short)(u >> 16));
    } else {
        float2 f = ((const float2*)xin)[(size_t)tok * 256 + t];
        v0 = f.x; v1 = f.y;
    }
    float s = v0 + v1, sq = v0 * v0 + v1 * v1;
    for (int off = 32; off; off >>= 1) {
        s  += __shfl_down(s, off);
        sq += __shfl_down(sq, off);
    }
    __shared__ float red[8];
    if ((t & 63) == 0) { red[t >> 6] = s; red[4 + (t >> 6)] = sq; }
    __syncthreads();
    float S  = red[0] + red[1] + red[2] + red[3];
    float SQ = red[4] + red[5] + red[6] + red[7];
    float mean = S * (1.0f / 512.0f);
    float var  = SQ * (1.0f / 512.0f) - mean * mean;
    float rstd = rsqrtf(var + 1e-5f);
    int c = t * 2;
    float y0 = (v0 - mean) * rstd * g[c]     + bb[c];
    float y1 = (v1 - mean) * rstd * g[c + 1] + bb[c + 1];
    ((unsigned*)out)[(size_t)tok * 256 + t] = (unsigned)f2b(y0) | ((unsigned)f2b(y1) << 16);
}

// ---------- GEMM: A[M][K] bf16, Bt[N][K] bf16 -> C[M][N] ----------
// 128x128 tile, 4 waves, BK=64 (two 32-K slabs), double-buffered LDS with
// post-barrier async prefetch (loads fly during the 32-MFMA compute phase).
// RESID: 0 none, 1 add f32 residual, 2 add bf16 residual.
template<int ACT, int BIAS, int RESID, int OUTBF>
__global__ __launch_bounds__(256) void gemm_bf16k(
    const unsigned short* __restrict__ A, const unsigned short* __restrict__ Bt,
    const float* __restrict__ bias, const void* Rres,
    void* Cout, int M, int N, int K)
{
    __shared__ __align__(16) unsigned short As[2][2][128 * 32];   // [buf][slab]
    __shared__ __align__(16) unsigned short Bs[2][2][128 * 32];
    int t = threadIdx.x;
    int bm = blockIdx.y, bn = blockIdx.x;
    int wave = t >> 6, lane = t & 63;
    int wm = wave >> 1, wn = wave & 1;
    int l15 = lane & 15, kg = lane >> 4;
    f32x4 acc[4][4];
    #pragma unroll
    for (int i = 0; i < 4; i++)
        #pragma unroll
        for (int j = 0; j < 4; j++)
            acc[i][j] = (f32x4){0.f, 0.f, 0.f, 0.f};
    int r0 = t >> 2, c0 = (t & 3) * 8;
    const unsigned short* gA = A  + (size_t)(bm * 128 + r0) * K + c0;
    const unsigned short* gB = Bt + (size_t)(bn * 128 + r0) * K + c0;
    auto stage = [&](int p, int kt) {
        #pragma unroll
        for (int kh = 0; kh < 2; kh++) {
            gl_lds16(gA + kt + kh * 32,                  &As[p][kh][t * 8]);
            gl_lds16(gA + kt + kh * 32 + (size_t)64 * K, &As[p][kh][t * 8 + 2048]);
            gl_lds16(gB + kt + kh * 32,                  &Bs[p][kh][t * 8]);
            gl_lds16(gB + kt + kh * 32 + (size_t)64 * K, &Bs[p][kh][t * 8 + 2048]);
        }
    };
    stage(0, 0);
    int p = 0;
    for (int kt = 0; kt < K; kt += 64) {
        __syncthreads();                     // drains buf[p] writes; frees buf[p^1] (reads done last iter)
        if (kt + 64 < K) stage(p ^ 1, kt + 64);   // prefetch: drained only at NEXT barrier
        #pragma unroll
        for (int kh = 0; kh < 2; kh++) {
            bf16x8 aF[4], bF[4];
            #pragma unroll
            for (int i = 0; i < 4; i++)
                aF[i] = *(const bf16x8*)&As[p][kh][(wm * 64 + i * 16 + l15) * 32 + kg * 8];
            #pragma unroll
            for (int j = 0; j < 4; j++)
                bF[j] = *(const bf16x8*)&Bs[p][kh][(wn * 64 + j * 16 + l15) * 32 + kg * 8];
            #pragma unroll
            for (int i = 0; i < 4; i++)
                #pragma unroll
                for (int j = 0; j < 4; j++)
                    acc[i][j] = __builtin_amdgcn_mfma_f32_16x16x32_bf16(aF[i], bF[j], acc[i][j], 0, 0, 0);
        }
        p ^= 1;
    }
    #pragma unroll
    for (int i = 0; i < 4; i++) {
        #pragma unroll
        for (int j = 0; j < 4; j++) {
            #pragma unroll
            for (int rg = 0; rg < 4; rg++) {
                int row = bm * 128 + wm * 64 + i * 16 + kg * 4 + rg;
                int col = bn * 128 + wn * 64 + j * 16 + l15;
                float v = acc[i][j][rg];
                if (BIAS) v += bias[col];
                if (ACT == 1) v = gelu_exact(v);
                if (RESID == 1) v += ((const float*)Rres)[(size_t)row * N + col];
                if (RESID == 2) v += b2f(((const unsigned short*)Rres)[(size_t)row * N + col]);
                if (OUTBF) ((unsigned short*)Cout)[(size_t)row * N + col] = f2b(v);
                else       ((float*)Cout)[(size_t)row * N + col] = v;
            }
        }
    }
}

// ---------- RoPE + normalize + fold scale, split qkv ----------
__global__ __launch_bounds__(256) void rope_qkv_ct(
    const float* __restrict__ qkv, const float* __restrict__ ls,
    float* __restrict__ qn, float* __restrict__ kn, float* __restrict__ vout)
{
    int tok = blockIdx.x;           // b*64+p
    int b = tok >> 6, p = tok & 63;
    int t = threadIdx.x;
    int h = t >> 5, r = t & 31;
    const float* base = qkv + (size_t)tok * 1536;
    float q0 = base[h * 64 + 2 * r], q1 = base[h * 64 + 2 * r + 1];
    float k0 = base[512 + h * 64 + 2 * r], k1 = base[512 + h * 64 + 2 * r + 1];
    int i = p >> 3, j = p & 7;
    int f = (r < 16) ? r : (r - 16);
    float mult = (r < 16) ? (float)i : (float)j;
    float freq = expf(-(float)f * (logf(10000.0f) / 16.0f));
    float ang = mult * freq;
    float sn, cs; sincosf(ang, &sn, &cs);
    float qr0 = q0 * cs - q1 * sn, qr1 = q0 * sn + q1 * cs;
    float kr0 = k0 * cs - k1 * sn, kr1 = k0 * sn + k1 * cs;
    float sq = qr0 * qr0 + qr1 * qr1;
    float sk = kr0 * kr0 + kr1 * kr1;
    for (int off = 16; off; off >>= 1) {
        sq += __shfl_xor(sq, off, 32);
        sk += __shfl_xor(sk, off, 32);
    }
    float scale = expf(fminf(ls[h], 4.6052f));
    float qf = scale / fmaxf(sqrtf(sq), 1e-12f);
    float kf = 1.0f  / fmaxf(sqrtf(sk), 1e-12f);
    size_t o = (((size_t)(b * 8 + h) * 64) + p) * 64 + 2 * r;
    qn[o] = qr0 * qf; qn[o + 1] = qr1 * qf;
    kn[o] = kr0 * kf; kn[o + 1] = kr1 * kf;
    int c0 = 2 * t;
    int vh = c0 >> 6, vd = c0 & 63;
    size_t vo = (((size_t)(b * 8 + vh) * 64) + p) * 64 + vd;
    vout[vo]     = base[1024 + c0];
    vout[vo + 1] = base[1024 + c0 + 1];
}

// ---------- CT attention (q,k pre-normalized&scaled) + residual ----------
__global__ __launch_bounds__(256) void attn_ct(
    const float* __restrict__ qn, const float* __restrict__ kn, const float* __restrict__ v,
    const float* __restrict__ ct_in, float* __restrict__ ct_out)
{
    int bh = blockIdx.x; int b = bh >> 3, h = bh & 7;
    int t = threadIdx.x;
    __shared__ __align__(16) float Sq[64 * 64];
    __shared__ __align__(16) float Sk[64 * 64];
    __shared__ __align__(16) float Ss[64 * 64];
    const float* qb = qn + (size_t)bh * 4096;
    const float* kb = kn + (size_t)bh * 4096;
    const float* vb = v  + (size_t)bh * 4096;
    for (int idx = t; idx < 1024; idx += 256) {
        ((float4*)Sq)[idx] = ((const float4*)qb)[idx];
        ((float4*)Sk)[idx] = ((const float4*)kb)[idx];
    }
    __syncthreads();
    int i = t >> 2, q4 = t & 3;
    {
        float acc[16];
        #pragma unroll
        for (int jj = 0; jj < 16; jj++) acc[jj] = 0.f;
        for (int k = 0; k < 64; k++) {
            float qv = Sq[i * 64 + k];
            #pragma unroll
            for (int jj = 0; jj < 16; jj++)
                acc[jj] += qv * Sk[(q4 * 16 + jj) * 64 + k];
        }
        float mx = -1e30f;
        #pragma unroll
        for (int jj = 0; jj < 16; jj++) mx = fmaxf(mx, acc[jj]);
        for (int off = 1; off < 4; off <<= 1) mx = fmaxf(mx, __shfl_xor(mx, off, 4));
        float sum = 0.f;
        #pragma unroll
        for (int jj = 0; jj < 16; jj++) { acc[jj] = expf(acc[jj] - mx); sum += acc[jj]; }
        for (int off = 1; off < 4; off <<= 1) sum += __shfl_xor(sum, off, 4);
        float inv = 1.f / sum;
        #pragma unroll
        for (int jj = 0; jj < 16; jj++) Ss[i * 64 + q4 * 16 + jj] = acc[jj] * inv;
    }
    __syncthreads();
    {
        int d0 = q4 * 16;
        float acc[16];
        #pragma unroll
        for (int dd = 0; dd < 16; dd++) acc[dd] = 0.f;
        for (int j = 0; j < 64; j++) {
            float pP = Ss[i * 64 + j];
            #pragma unroll
            for (int dd = 0; dd < 16; dd++) acc[dd] += pP * vb[j * 64 + d0 + dd];
        }
        size_t orow = ((size_t)(b * 64 + i)) * 512 + h * 64 + d0;
        #pragma unroll
        for (int dd = 0; dd < 16; dd++) ct_out[orow + dd] = ct_in[orow + dd] + acc[dd];
    }
}

// ---------- assemble z (bf16) = [ct_token ; 64 window pixels], f32 sources ----------
__global__ void assemble_z(const float* __restrict__ x, const float* __restrict__ ctf,
                           unsigned short* __restrict__ z) {
    int gid = blockIdx.x * 256 + threadIdx.x;   // 512*65*128 groups of 4
    if (gid >= 512 * 65 * 128) return;
    int c4 = gid & 127, tk = gid >> 7;
    int win = tk / 65, tok = tk - win * 65;
    float4 v;
    if (tok == 0) {
        v = ((const float4*)ctf)[(size_t)win * 128 + c4];
    } else {
        int p = tok - 1;
        int b = win >> 6, wh = (win >> 3) & 7, ww = win & 7;
        size_t pix = ((size_t)(b * 64 + wh * 8 + (p >> 3)) * 64) + ww * 8 + (p & 7);
        v = ((const float4*)x)[pix * 128 + c4];
    }
    ushort4 u;
    u.x = f2b(v.x); u.y = f2b(v.y); u.z = f2b(v.z); u.w = f2b(v.w);
    ((ushort4*)z)[gid] = u;
}

// ---------- CPB: tb[225][8], f32 weights ----------
__global__ void cpb_tb(const float* __restrict__ w1, const float* __restrict__ b1,
                       const float* __restrict__ w2, float* __restrict__ tb) {
    int pos = blockIdx.x;   // 0..224
    int t = threadIdx.x;
    int a = pos / 15, bq = pos % 15;
    float t0 = ((float)(a  - 7)) / 7.0f * 8.0f;
    float t1 = ((float)(bq - 7)) / 7.0f * 8.0f;
    float l8 = log2f(8.0f);
    float x0 = copysignf(log2f(fabsf(t0) + 1.0f) / l8, t0);
    float x1 = copysignf(log2f(fabsf(t1) + 1.0f) / l8, t1);
    __shared__ float acc8[8];
    if (t < 8) acc8[t] = 0.f;
    __syncthreads();
    float partial[8] = {0, 0, 0, 0, 0, 0, 0, 0};
    for (int u = t; u < 512; u += 256) {
        float hv = fmaxf(x0 * w1[u] + x1 * w1[512 + u] + b1[u], 0.0f);
        #pragma unroll
        for (int hh = 0; hh < 8; hh++) partial[hh] += hv * w2[u * 8 + hh];
    }
    for (int hh = 0; hh < 8; hh++) atomicAdd(&acc8[hh], partial[hh]);
    __syncthreads();
    if (t < 8) tb[pos * 8 + t] = acc8[t];
}

// ---------- bias[8][65][65] ----------
__global__ void bias_fill(const float* __restrict__ tb, float* __restrict__ bias) {
    int idx = blockIdx.x * 256 + threadIdx.x;
    if (idx >= 8 * 65 * 65) return;
    int h = idx / 4225, rem = idx % 4225;
    int i = rem / 65, j = rem % 65;
    float val = 0.f;
    if (i > 0 && j > 0) {
        int ii = i - 1, jj = j - 1;
        int d0 = (ii >> 3) - (jj >> 3) + 7;
        int d1 = (ii & 7) - (jj & 7) + 7;
        float xv = tb[(d0 * 15 + d1) * 8 + h];
        val = 16.0f / (1.0f + expf(-xv));
    }
    bias[idx] = val;
}

// ---------- window attention via MFMA (chunk-local windows) ----------
__global__ __launch_bounds__(256) void attn_win(
    const unsigned short* __restrict__ qkv, const float* __restrict__ ls,
    const float* __restrict__ bias, unsigned short* __restrict__ obuf)
{
    int win = blockIdx.x >> 3, h = blockIdx.x & 7;   // chunk-local window
    int t = threadIdx.x;
    int wave = t >> 6, lane = t & 63, l15 = lane & 15, kg = lane >> 4;
    __shared__ __align__(16) unsigned short U[11520];     // Sq[5760]+Sk[5760]; reused as Sp[8320]
    __shared__ __align__(16) unsigned short SvT[64 * 104];
    __shared__ __align__(16) float Ss[65 * 68];
    __shared__ float qfac[65], kfac[65];
    unsigned short* Sq = U;
    unsigned short* Sk = U + 5760;
    unsigned short* Sp = U;

    for (int idx = t; idx < 15 * 18; idx += 256) {
        int r = 65 + idx / 18, c4 = (idx % 18) * 4;
        *(ushort4*)&Sq[r * 72 + c4] = (ushort4){0, 0, 0, 0};
        *(ushort4*)&Sk[r * 72 + c4] = (ushort4){0, 0, 0, 0};
    }
    for (int idx = t; idx < 64 * 26; idx += 256)
        *(ushort4*)&SvT[idx * 4] = (ushort4){0, 0, 0, 0};
    __syncthreads();
    const unsigned short* base = qkv + (size_t)win * 65 * 1536 + h * 64;
    for (int idx = t; idx < 65 * 16; idx += 256) {
        int r = idx >> 4, d4 = (idx & 15) * 4;
        const unsigned short* rp = base + (size_t)r * 1536 + d4;
        ushort4 uq = *(const ushort4*)rp;
        ushort4 uk = *(const ushort4*)(rp + 512);
        ushort4 uv = *(const ushort4*)(rp + 1024);
        *(ushort4*)&Sq[r * 72 + d4] = uq;
        *(ushort4*)&Sk[r * 72 + d4] = uk;
        SvT[(d4 + 0) * 104 + r] = uv.x;
        SvT[(d4 + 1) * 104 + r] = uv.y;
        SvT[(d4 + 2) * 104 + r] = uv.z;
        SvT[(d4 + 3) * 104 + r] = uv.w;
    }
    __syncthreads();
    if (t < 130) {
        int r = (t < 65) ? t : (t - 65);
        const unsigned short* row = ((t < 65) ? Sq : Sk) + r * 72;
        float s = 0.f;
        for (int d = 0; d < 64; d++) { float v = b2f(row[d]); s += v * v; }
        float f = 1.0f / fmaxf(sqrtf(s), 1e-12f);
        if (t < 65) qfac[r] = f * expf(fminf(ls[h], 4.6052f));
        else        kfac[r] = f;
    }
    __syncthreads();
    for (int s = wave; s < 25; s += 4) {
        int tm = s / 5, tn = s % 5;
        f32x4 acc = (f32x4){0.f, 0.f, 0.f, 0.f};
        #pragma unroll
        for (int kk = 0; kk < 2; kk++) {
            bf16x8 aF = *(const bf16x8*)&Sq[(tm * 16 + l15) * 72 + kk * 32 + kg * 8];
            bf16x8 bF = *(const bf16x8*)&Sk[(tn * 16 + l15) * 72 + kk * 32 + kg * 8];
            acc = __builtin_amdgcn_mfma_f32_16x16x32_bf16(aF, bF, acc, 0, 0, 0);
        }
        #pragma unroll
        for (int rg = 0; rg < 4; rg++) {
            int i = tm * 16 + kg * 4 + rg, j = tn * 16 + l15;
            if (i < 65 && j < 65)
                Ss[i * 68 + j] = acc[rg] * qfac[i] * kfac[j] + bias[(size_t)h * 4225 + i * 65 + j];
        }
    }
    __syncthreads();
    for (int idx = t; idx < 80 * 26; idx += 256)
        *(ushort4*)&Sp[idx * 4] = (ushort4){0, 0, 0, 0};
    __syncthreads();
    if (t < 65) {
        float mx = -1e30f;
        for (int j = 0; j < 65; j++) mx = fmaxf(mx, Ss[t * 68 + j]);
        float sum = 0.f;
        for (int j = 0; j < 65; j++) { float e = expf(Ss[t * 68 + j] - mx); Ss[t * 68 + j] = e; sum += e; }
        float inv = 1.f / sum;
        for (int j = 0; j < 65; j++) Sp[t * 104 + j] = f2b(Ss[t * 68 + j] * inv);
    }
    __syncthreads();
    for (int s = wave; s < 20; s += 4) {
        int tm = s >> 2, tn = s & 3;
        f32x4 acc = (f32x4){0.f, 0.f, 0.f, 0.f};
        #pragma unroll
        for (int kk = 0; kk < 3; kk++) {
            bf16x8 aF = *(const bf16x8*)&Sp[(tm * 16 + l15) * 104 + kk * 32 + kg * 8];
            bf16x8 bF = *(const bf16x8*)&SvT[(tn * 16 + l15) * 104 + kk * 32 + kg * 8];
            acc = __builtin_amdgcn_mfma_f32_16x16x32_bf16(aF, bF, acc, 0, 0, 0);
        }
        #pragma unroll
        for (int rg = 0; rg < 4; rg++) {
            int i = tm * 16 + kg * 4 + rg, d = tn * 16 + l15;
            if (i < 65)
                obuf[((size_t)(win * 65 + i)) * 512 + h * 64 + d] = f2b(acc[rg]);
        }
    }
}

// ---------- window reverse: z[:,1:,:] (bf16) -> x_out f32 ----------
__global__ void reverse_z(const unsigned short* __restrict__ z, float* __restrict__ out) {
    int gid = blockIdx.x * 256 + threadIdx.x;   // 8*64*64*128 groups of 4
    if (gid >= 8 * 64 * 64 * 128) return;
    int c4 = gid & 127, pix = gid >> 7;
    int b = pix >> 12, rem = pix & 4095;
    int hh = rem >> 6, w_ = rem & 63;
    int win = b * 64 + (hh >> 3) * 8 + (w_ >> 3);
    int tok = 1 + (hh & 7) * 8 + (w_ & 7);
    ushort4 u = ((const ushort4*)z)[((size_t)(win * 65 + tok)) * 128 + c4];
    float4 v;
    v.x = b2f(u.x); v.y = b2f(u.y); v.z = b2f(u.z); v.w = b2f(u.w);
    ((float4*)out)[gid] = v;
}

extern "C" void kernel_launch(void* const* d_in, const int* in_sizes, int n_in,
                              void* d_out, int out_size, void* d_ws, size_t ws_size,
                              hipStream_t stream)
{
    const float* x        = (const float*)d_in[0];
    const float* ct       = (const float*)d_in[1];
    const float* w_qkv_ct = (const float*)d_in[2];
    const float* ls_ct    = (const float*)d_in[3];
    const float* g_ct1    = (const float*)d_in[4];
    const float* b_ct1    = (const float*)d_in[5];
    const float* g_ct2    = (const float*)d_in[6];
    const float* b_ct2    = (const float*)d_in[7];
    const float* w1_ct    = (const float*)d_in[8];
    const float* b1_ct    = (const float*)d_in[9];
    const float* w2_ct    = (const float*)d_in[10];
    const float* b2_ct    = (const float*)d_in[11];
    const float* w_qkv_w  = (const float*)d_in[12];
    const float* w_proj   = (const float*)d_in[13];
    const float* b_proj   = (const float*)d_in[14];
    const float* ls_w     = (const float*)d_in[15];
    const float* g_w1     = (const float*)d_in[16];
    const float* b_w1     = (const float*)d_in[17];
    const float* g_w2     = (const float*)d_in[18];
    const float* b_w2     = (const float*)d_in[19];
    const float* cpb_w1   = (const float*)d_in[20];
    const float* cpb_b1   = (const float*)d_in[21];
    const float* cpb_w2   = (const float*)d_in[22];
    const float* w1_w     = (const float*)d_in[23];
    const float* b1_w     = (const float*)d_in[24];
    const float* w2_w     = (const float*)d_in[25];
    const float* b2_w     = (const float*)d_in[26];

    char* wsb = (char*)d_ws;
    size_t off = 0;
    auto alloc = [&](size_t bytes) -> char* {
        char* p = wsb + off;
        off += (bytes + 255) & ~((size_t)255);
        return p;
    };
    // ---- persistent region ----
    unsigned short* wqkvw_t = (unsigned short*)alloc((size_t)1536 * 512 * 2);
    unsigned short* wproj_t = (unsigned short*)alloc((size_t)512 * 512 * 2);
    unsigned short* w1w_t   = (unsigned short*)alloc((size_t)2048 * 512 * 2);
    unsigned short* w2w_t   = (unsigned short*)alloc((size_t)512 * 2048 * 2);
    float* ct_work = (float*)alloc((size_t)512 * 512 * 4);
    float* tb      = (float*)alloc((size_t)225 * 8 * 4);
    float* biasw   = (float*)alloc((size_t)8 * 65 * 65 * 4);
    unsigned short* z = (unsigned short*)alloc((size_t)33280 * 512 * 2);
    size_t ubase = off;

    // ---- chunk size: 2 chunks if workspace allows, else 4 (proven) ----
    size_t need2 = ubase + (size_t)16640 * 5120 + 4096;
    int CH = (ws_size >= need2) ? 16640 : 8320;
    int nc = 33280 / CH, NB = CH / 128;

    // ---- window union region ----
    unsigned short* h2c   = (unsigned short*)(wsb + ubase);              // CH*1024 B (also obufc)
    unsigned short* qkvc  = (unsigned short*)(wsb + ubase + (size_t)CH * 1024);  // CH*3072 B
    unsigned short* obufc = h2c;
    unsigned short* midw  = qkvc;   // CH*4096 B (qkvc + spare)

    // ---- CT scratch overlays the union region (time-disjoint) ----
    {
        size_t coff = ubase;
        auto calloc_ = [&](size_t bytes) -> char* {
            char* p = wsb + coff;
            coff += (bytes + 255) & ~((size_t)255);
            return p;
        };
        unsigned short* wqkvct_t = (unsigned short*)calloc_((size_t)1536 * 512 * 2);
        unsigned short* w1ct_t   = (unsigned short*)calloc_((size_t)2048 * 512 * 2);
        unsigned short* w2ct_t   = (unsigned short*)calloc_((size_t)512 * 2048 * 2);
        unsigned short* h_ct     = (unsigned short*)calloc_((size_t)512 * 512 * 2);
        float* qkv_ct = (float*)calloc_((size_t)512 * 1536 * 4);
        float* qn_ct  = (float*)calloc_((size_t)8 * 8 * 64 * 64 * 4);
        float* kn_ct  = (float*)calloc_((size_t)8 * 8 * 64 * 64 * 4);
        float* v_ct   = (float*)calloc_((size_t)8 * 8 * 64 * 64 * 4);
        unsigned short* midc = (unsigned short*)calloc_((size_t)512 * 2048 * 2);

        // weight transposes (f32 [R][C] -> bf16 [C][R])
        transpose_f2b<<<dim3(48, 16), 256, 0, stream>>>(w_qkv_ct, wqkvct_t, 512, 1536);
        transpose_f2b<<<dim3(64, 16), 256, 0, stream>>>(w1_ct, w1ct_t, 512, 2048);
        transpose_f2b<<<dim3(16, 64), 256, 0, stream>>>(w2_ct, w2ct_t, 2048, 512);
        transpose_f2b<<<dim3(48, 16), 256, 0, stream>>>(w_qkv_w, wqkvw_t, 512, 1536);
        transpose_f2b<<<dim3(16, 16), 256, 0, stream>>>(w_proj, wproj_t, 512, 512);
        transpose_f2b<<<dim3(64, 16), 256, 0, stream>>>(w1_w, w1w_t, 512, 2048);
        transpose_f2b<<<dim3(16, 64), 256, 0, stream>>>(w2_w, w2w_t, 2048, 512);

        // --- CT branch ---
        ln_bf16<0><<<512, 256, 0, stream>>>(ct, g_ct1, b_ct1, h_ct);
        gemm_bf16k<0, 0, 0, 0><<<dim3(12, 4), 256, 0, stream>>>(h_ct, wqkvct_t, nullptr, nullptr, qkv_ct, 512, 1536, 512);
        rope_qkv_ct<<<512, 256, 0, stream>>>(qkv_ct, ls_ct, qn_ct, kn_ct, v_ct);
        attn_ct<<<64, 256, 0, stream>>>(qn_ct, kn_ct, v_ct, ct, ct_work);
        ln_bf16<0><<<512, 256, 0, stream>>>(ct_work, g_ct2, b_ct2, h_ct);
        gemm_bf16k<1, 1, 0, 1><<<dim3(16, 4), 256, 0, stream>>>(h_ct, w1ct_t, b1_ct, nullptr, midc, 512, 2048, 512);
        gemm_bf16k<0, 1, 1, 0><<<dim3(4, 4), 256, 0, stream>>>(midc, w2ct_t, b2_ct, ct_work, ct_work, 512, 512, 2048);
    }

    // --- window branch ---
    assemble_z<<<16640, 256, 0, stream>>>(x, ct_work, z);
    cpb_tb<<<225, 256, 0, stream>>>(cpb_w1, cpb_b1, cpb_w2, tb);
    bias_fill<<<133, 256, 0, stream>>>(tb, biasw);

    for (int c = 0; c < nc; c++) {
        size_t rowoff = (size_t)c * CH;
        ln_bf16<1><<<CH, 256, 0, stream>>>(z + rowoff * 512, g_w1, b_w1, h2c);
        gemm_bf16k<0, 0, 0, 1><<<dim3(12, NB), 256, 0, stream>>>(h2c, wqkvw_t, nullptr, nullptr, qkvc, CH, 1536, 512);
        attn_win<<<(CH / 65) * 8, 256, 0, stream>>>(qkvc, ls_w, biasw, obufc);
        gemm_bf16k<0, 1, 2, 1><<<dim3(4, NB), 256, 0, stream>>>(obufc, wproj_t, b_proj, z + rowoff * 512, z + rowoff * 512, CH, 512, 512);
    }
    for (int c = 0; c < nc; c++) {
        size_t rowoff = (size_t)c * CH;
        ln_bf16<1><<<CH, 256, 0, stream>>>(z + rowoff * 512, g_w2, b_w2, h2c);
        gemm_bf16k<1, 1, 0, 1><<<dim3(16, NB), 256, 0, stream>>>(h2c, w1w_t, b1_w, nullptr, midw, CH, 2048, 512);
        gemm_bf16k<0, 1, 2, 1><<<dim3(4, NB), 256, 0, stream>>>(midw, w2w_t, b2_w, z + rowoff * 512, z + rowoff * 512, CH, 512, 2048);
    }
    reverse_z<<<16384, 256, 0, stream>>>(z, (float*)d_out);
}